// Round 1
// baseline (586.858 us; speedup 1.0000x reference)
//
#include <hip/hip_runtime.h>
#include <hip/hip_bf16.h>
#include <stdint.h>

// Problem: 2-layer GCN (PyG GCNConv semantics) + global mean pool + 2-layer MLP.
// N=100000 nodes, E=1600000 edges, G=512 graphs. All fp32; indices int32.
//
// Layer 1 input is [N,1] => layer-1 aggregation collapses to a scalar t[i]:
//   t[i] = sum_{e: dst=i} x[src]*dinv[src]*dinv[i] + x[i]*dinv[i]^2
//   h1[i,j] = relu(t[i]*W1[j] + b1[j])
// Layer 2: xw2 = h1 @ W2 [N,128]; agg2[i] = sum msg + xw2[i]*dinv[i]^2; h2 = relu(agg2+b2)
// Pool: batch is sorted -> contiguous per-graph ranges via binary search (no atomics).

#define SCAN_T 256
#define SCAN_I 4

static inline size_t align_up(size_t x, size_t a){ return (x + a - 1) & ~(a - 1); }

__global__ void k_count(const int* __restrict__ dst, int* __restrict__ deg, int E){
    int e = blockIdx.x * blockDim.x + threadIdx.x;
    if (e < E) atomicAdd(&deg[dst[e]], 1);
}

__global__ void k_dinv(const int* __restrict__ deg, float* __restrict__ dinv, int N){
    int i = blockIdx.x * blockDim.x + threadIdx.x;
    if (i < N) dinv[i] = rsqrtf((float)deg[i] + 1.0f);
}

__global__ void k_scanA(const int* __restrict__ deg, int* __restrict__ offs,
                        int* __restrict__ bsum, int n){
    __shared__ int sh[SCAN_T];
    int t = threadIdx.x;
    int base = blockIdx.x * (SCAN_T * SCAN_I) + t * SCAN_I;
    int v[SCAN_I];
    int sum = 0;
    #pragma unroll
    for (int u = 0; u < SCAN_I; ++u){
        int idx = base + u;
        v[u] = (idx < n) ? deg[idx] : 0;
        sum += v[u];
    }
    sh[t] = sum; __syncthreads();
    for (int off = 1; off < SCAN_T; off <<= 1){
        int xv = (t >= off) ? sh[t - off] : 0;
        __syncthreads();
        if (t >= off) sh[t] += xv;
        __syncthreads();
    }
    int run = (t == 0) ? 0 : sh[t - 1];
    #pragma unroll
    for (int u = 0; u < SCAN_I; ++u){
        int idx = base + u;
        if (idx < n) offs[idx] = run;
        run += v[u];
    }
    if (t == SCAN_T - 1) bsum[blockIdx.x] = sh[SCAN_T - 1];
}

__global__ void k_scanB(int* __restrict__ bsum, int nb){
    __shared__ int sh[SCAN_T];
    int t = threadIdx.x;
    sh[t] = (t < nb) ? bsum[t] : 0; __syncthreads();
    for (int off = 1; off < SCAN_T; off <<= 1){
        int xv = (t >= off) ? sh[t - off] : 0;
        __syncthreads();
        if (t >= off) sh[t] += xv;
        __syncthreads();
    }
    int excl = (t == 0) ? 0 : sh[t - 1];
    if (t < nb) bsum[t] = excl;
}

__global__ void k_scanC(int* __restrict__ offs, int* __restrict__ cursor,
                        const int* __restrict__ bsum, int n, int Etot){
    int t = threadIdx.x;
    int base = blockIdx.x * (SCAN_T * SCAN_I) + t * SCAN_I;
    int add = bsum[blockIdx.x];
    #pragma unroll
    for (int u = 0; u < SCAN_I; ++u){
        int idx = base + u;
        if (idx < n){
            int v = offs[idx] + add;
            offs[idx] = v;
            cursor[idx] = v;
        }
    }
    if (blockIdx.x == 0 && t == 0) offs[n] = Etot;
}

__global__ void k_fill(const int* __restrict__ src, const int* __restrict__ dst,
                       const float* __restrict__ x, const float* __restrict__ dinv,
                       int* __restrict__ cursor, int2* __restrict__ csr,
                       float* __restrict__ tacc, int E){
    int e = blockIdx.x * blockDim.x + threadIdx.x;
    if (e >= E) return;
    int s = src[e], d = dst[e];
    float nrm = dinv[s] * dinv[d];
    int slot = atomicAdd(&cursor[d], 1);
    csr[slot] = make_int2(s, __float_as_int(nrm));
    atomicAdd(&tacc[d], x[s] * nrm);
}

// xw2[i,:] = h1(t[i]) @ W2, 128 cols. 256 threads = 2 nodes; W2 column in regs.
__global__ void __launch_bounds__(256) k_xw2(
        const float* __restrict__ x, const float* __restrict__ dinv,
        const float* __restrict__ tacc,
        const float* __restrict__ W1, const float* __restrict__ b1,
        const float* __restrict__ W2, float* __restrict__ xw2, int N){
    int col = threadIdx.x & 127;
    int sub = threadIdx.x >> 7;
    float w2c[64];
    #pragma unroll
    for (int j = 0; j < 64; ++j) w2c[j] = W2[j * 128 + col];
    int npairs = (N + 1) >> 1;
    for (int p = blockIdx.x; p < npairs; p += gridDim.x){
        int i = p * 2 + sub;
        if (i < N){
            float di = dinv[i];
            float tv = fmaf(x[i] * di, di, tacc[i]);
            float acc = 0.f;
            #pragma unroll
            for (int j = 0; j < 64; ++j){
                float h = fmaxf(fmaf(tv, W1[j], b1[j]), 0.f);
                acc = fmaf(h, w2c[j], acc);
            }
            xw2[(size_t)i * 128 + col] = acc;
        }
    }
}

// One wave per dst node; lane holds 2 cols (float2). Register accumulation, no atomics.
__global__ void __launch_bounds__(256) k_agg2(
        const int2* __restrict__ csr, const int* __restrict__ offs,
        const float* __restrict__ dinv, const float* __restrict__ xw2,
        const float* __restrict__ b2, float* __restrict__ h2, int N){
    int w = (int)((blockIdx.x * blockDim.x + threadIdx.x) >> 6);
    if (w >= N) return;
    int lane = threadIdx.x & 63;
    int beg = offs[w], end = offs[w + 1];
    const float2* xv = (const float2*)xw2;
    float ax = 0.f, ay = 0.f;
    int k = beg;
    for (; k + 1 < end; k += 2){
        int2 e0 = csr[k];
        int2 e1 = csr[k + 1];
        float n0 = __int_as_float(e0.y);
        float n1 = __int_as_float(e1.y);
        float2 v0 = xv[(size_t)e0.x * 64 + lane];
        float2 v1 = xv[(size_t)e1.x * 64 + lane];
        ax = fmaf(v0.x, n0, ax); ay = fmaf(v0.y, n0, ay);
        ax = fmaf(v1.x, n1, ax); ay = fmaf(v1.y, n1, ay);
    }
    if (k < end){
        int2 e0 = csr[k];
        float n0 = __int_as_float(e0.y);
        float2 v0 = xv[(size_t)e0.x * 64 + lane];
        ax = fmaf(v0.x, n0, ax); ay = fmaf(v0.y, n0, ay);
    }
    float di = dinv[w];
    float sw = di * di;
    float2 vs = xv[(size_t)w * 64 + lane];
    ax = fmaf(vs.x, sw, ax); ay = fmaf(vs.y, sw, ay);
    float2 bb = ((const float2*)b2)[lane];
    float2 r;
    r.x = fmaxf(ax + bb.x, 0.f);
    r.y = fmaxf(ay + bb.y, 0.f);
    ((float2*)h2)[(size_t)w * 64 + lane] = r;
}

// One block per graph: mean pool (binary search on sorted batch) + 2-layer head.
__global__ void __launch_bounds__(128) k_poolhead(
        const float* __restrict__ h2, const int* __restrict__ batch,
        const float* __restrict__ Wl1, const float* __restrict__ bl1,
        const float* __restrict__ Wl2, const float* __restrict__ bl2,
        float* __restrict__ out, int N){
    __shared__ float pooled[128];
    __shared__ float h3s[64];
    int g = blockIdx.x;
    int c = threadIdx.x;  // 128 threads
    int lo = 0, hi = N;
    while (lo < hi){ int m = (lo + hi) >> 1; if (batch[m] < g) lo = m + 1; else hi = m; }
    int lo2 = lo, hi2 = N;
    while (lo2 < hi2){ int m = (lo2 + hi2) >> 1; if (batch[m] < g + 1) lo2 = m + 1; else hi2 = m; }
    float acc = 0.f;
    for (int i = lo; i < lo2; ++i) acc += h2[(size_t)i * 128 + c];
    int cnt = lo2 - lo;
    pooled[c] = acc / (float)(cnt > 0 ? cnt : 1);
    __syncthreads();
    if (c < 64){
        float a = bl1[c];
        #pragma unroll
        for (int k = 0; k < 128; ++k) a = fmaf(pooled[k], Wl1[k * 64 + c], a);
        h3s[c] = fmaxf(a, 0.f);
    }
    __syncthreads();
    if (c < 4){
        float o = bl2[c];
        #pragma unroll
        for (int j = 0; j < 64; ++j) o = fmaf(h3s[j], Wl2[j * 4 + c], o);
        out[g * 4 + c] = o;
    }
}

extern "C" void kernel_launch(void* const* d_in, const int* in_sizes, int n_in,
                              void* d_out, int out_size, void* d_ws, size_t ws_size,
                              hipStream_t stream) {
    const float* x    = (const float*)d_in[0];
    const int*   ei   = (const int*)d_in[1];
    const int*   batch= (const int*)d_in[2];
    const float* W1   = (const float*)d_in[3];
    const float* b1   = (const float*)d_in[4];
    const float* W2   = (const float*)d_in[5];
    const float* b2   = (const float*)d_in[6];
    const float* Wl1  = (const float*)d_in[7];
    const float* bl1  = (const float*)d_in[8];
    const float* Wl2  = (const float*)d_in[9];
    const float* bl2  = (const float*)d_in[10];

    const int N = in_sizes[0];
    const int E = in_sizes[1] / 2;
    const int G = out_size / 4;
    const int* src = ei;
    const int* dst = ei + E;

    // Workspace layout (re-poisoned to 0xAA before each call -> rebuild everything)
    char* p = (char*)d_ws;
    size_t off = 0;
    int*   deg    = (int*)(p + off);   off += align_up((size_t)N * 4, 16);
    float* tacc   = (float*)(p + off); off += align_up((size_t)N * 4, 16);
    size_t zero_bytes = off;  // deg + tacc must start at 0
    int*   offs   = (int*)(p + off);   off += align_up((size_t)(N + 1) * 4, 16);
    int*   cursor = (int*)(p + off);   off += align_up((size_t)N * 4, 16);
    int*   bsum   = (int*)(p + off);   off += align_up((size_t)SCAN_T * 4, 16);
    float* dinv   = (float*)(p + off); off += align_up((size_t)N * 4, 16);
    int2*  csr    = (int2*)(p + off);  off += align_up((size_t)E * 8, 16);
    float* xw2    = (float*)(p + off); off += align_up((size_t)N * 128 * 4, 16);
    float* h2     = (float*)(p + off); off += align_up((size_t)N * 128 * 4, 16);
    (void)ws_size; (void)n_in;

    hipMemsetAsync(d_ws, 0, zero_bytes, stream);

    const int TB = 256;
    k_count<<<(E + TB - 1) / TB, TB, 0, stream>>>(dst, deg, E);
    k_dinv<<<(N + TB - 1) / TB, TB, 0, stream>>>(deg, dinv, N);

    const int NB = (N + SCAN_T * SCAN_I - 1) / (SCAN_T * SCAN_I);  // <= 256
    k_scanA<<<NB, SCAN_T, 0, stream>>>(deg, offs, bsum, N);
    k_scanB<<<1, SCAN_T, 0, stream>>>(bsum, NB);
    k_scanC<<<NB, SCAN_T, 0, stream>>>(offs, cursor, bsum, N, E);

    k_fill<<<(E + TB - 1) / TB, TB, 0, stream>>>(src, dst, x, dinv, cursor, csr, tacc, E);
    k_xw2<<<4096, 256, 0, stream>>>(x, dinv, tacc, W1, b1, W2, xw2, N);
    k_agg2<<<(N + 3) / 4, 256, 0, stream>>>(csr, offs, dinv, xw2, b2, h2, N);
    k_poolhead<<<G, 128, 0, stream>>>(h2, batch, Wl1, bl1, Wl2, bl2, (float*)d_out, N);
}